// Round 13
// baseline (189.846 us; speedup 1.0000x reference)
//
#include <hip/hip_runtime.h>
#include <math.h>

#define IN_C 128
#define HID_C 64
#define OUT_C 40

// ---- grid-stride int4 zero ----
__global__ void zero4_kernel(int4* __restrict__ p, long long n4) {
  long long i = (long long)blockIdx.x * blockDim.x + threadIdx.x;
  long long stride = (long long)gridDim.x * blockDim.x;
  for (; i < n4; i += stride) p[i] = make_int4(0, 0, 0, 0);
}

// ---- scan stage 1: per-1024-chunk inclusive scan + chunk totals ----
__global__ __launch_bounds__(256) void scan1_kernel(
    const int* __restrict__ deg, int* __restrict__ S, int* __restrict__ BS,
    int n) {
  __shared__ int sums[256];
  int t = threadIdx.x;
  int i0 = blockIdx.x * 1024 + t * 4;
  int v0 = (i0 + 0 < n) ? deg[i0 + 0] : 0;
  int v1 = (i0 + 1 < n) ? deg[i0 + 1] : 0;
  int v2 = (i0 + 2 < n) ? deg[i0 + 2] : 0;
  int v3 = (i0 + 3 < n) ? deg[i0 + 3] : 0;
  v1 += v0; v2 += v1; v3 += v2;
  sums[t] = v3;
  __syncthreads();
  for (int off = 1; off < 256; off <<= 1) {
    int x = (t >= off) ? sums[t - off] : 0;
    __syncthreads();
    sums[t] += x;
    __syncthreads();
  }
  int excl = t ? sums[t - 1] : 0;
  if (i0 + 0 < n) S[i0 + 0] = v0 + excl;
  if (i0 + 1 < n) S[i0 + 1] = v1 + excl;
  if (i0 + 2 < n) S[i0 + 2] = v2 + excl;
  if (i0 + 3 < n) S[i0 + 3] = v3 + excl;
  if (t == 255) BS[blockIdx.x] = sums[255];
}

// ---- scan stage 2: exclusive scan of chunk totals (nb <= 128) ----
__global__ __launch_bounds__(128) void scan2_kernel(int* __restrict__ BS,
                                                    int nb) {
  __shared__ int s[128];
  int t = threadIdx.x;
  s[t] = (t < nb) ? BS[t] : 0;
  __syncthreads();
  for (int off = 1; off < 128; off <<= 1) {
    int x = (t >= off) ? s[t - off] : 0;
    __syncthreads();
    s[t] += x;
    __syncthreads();
  }
  if (t < nb) BS[t] = t ? s[t - 1] : 0;
}

// ---- scan stage 3: rowptr + dinv ----
__global__ void scan3_kernel(const int* __restrict__ S,
                             const int* __restrict__ BS,
                             const int* __restrict__ deg,
                             int* __restrict__ rowptr,
                             float* __restrict__ dinv, int n) {
  int i = blockIdx.x * blockDim.x + threadIdx.x;
  if (i < n) {
    int d = deg[i];
    int r = S[i] + BS[i >> 10];      // inclusive prefix = rowptr[i+1]
    rowptr[i + 1] = r;
    dinv[i] = rsqrtf((float)d + 1.0f);
    if (i == 0) rowptr[0] = 0;
  }
}

// ---- fused: blocks [0,DP_BLOCKS): degpos (deg count + slot claim);
//      blocks [DP_BLOCKS,...): y = x @ W1 raw (no dinv; independent) ----
#define XS_LD 68   // 64 + 4: float4-aligned, banks spread
#define DP_BLOCKS 1024
__global__ __launch_bounds__(256) void fused_degpos_gemm1_kernel(
    const int* __restrict__ dst, int E, int* __restrict__ deg,
    int* __restrict__ pos, const float* __restrict__ x,
    const float* __restrict__ W1, float* __restrict__ y, int n) {
  __shared__ float xs[64 * XS_LD];    // 17.4 KiB
  __shared__ float wsh[64 * HID_C];   // 16 KiB, [k][j]
  int t = threadIdx.x;
  if ((int)blockIdx.x < DP_BLOCKS) {
    // ---- degpos: pos[e] = atomicAdd(deg[dst[e]],1); 4-deep MLP ----
    int base = blockIdx.x * 256 + t;
    int stride = DP_BLOCKS * 256;
    for (int e = base; e < E; e += 4 * stride) {
      int e1 = e + stride, e2 = e + 2 * stride, e3 = e + 3 * stride;
      bool g1 = e1 < E, g2 = e2 < E, g3 = e3 < E;
      int d0 = dst[e];
      int d1 = g1 ? dst[e1] : 0;
      int d2 = g2 ? dst[e2] : 0;
      int d3 = g3 ? dst[e3] : 0;
      int p0 = atomicAdd(&deg[d0], 1);
      int p1 = g1 ? atomicAdd(&deg[d1], 1) : 0;
      int p2 = g2 ? atomicAdd(&deg[d2], 1) : 0;
      int p3 = g3 ? atomicAdd(&deg[d3], 1) : 0;
      pos[e] = p0;                    // coalesced stores
      if (g1) pos[e1] = p1;
      if (g2) pos[e2] = p2;
      if (g3) pos[e3] = p3;
    }
    return;
  }
  // ---- GEMM1 raw: 64x64 tile, K chunked by 64, 4x4 reg tile ----
  int rowBase = ((int)blockIdx.x - DP_BLOCKS) * 64;
  const float4* xf4 = (const float4*)x;
  const float4* wf4 = (const float4*)W1;
  int tx = t & 15, ty = t >> 4;
  int i0 = ty * 4, j0 = tx * 4;
  float acc[4][4];
#pragma unroll
  for (int r = 0; r < 4; ++r)
#pragma unroll
    for (int j = 0; j < 4; ++j) acc[r][j] = 0.f;

  for (int kc = 0; kc < 2; ++kc) {           // K chunks of 64
#pragma unroll
    for (int k = 0; k < 4; ++k) {
      int t4 = t + k * 256;                  // 0..1023
      int row = t4 >> 4, c4 = t4 & 15;
      int gr = rowBase + row;
      if (gr >= n) gr = n - 1;
      *(float4*)&xs[row * XS_LD + c4 * 4] = xf4[(size_t)gr * 32 + kc * 16 + c4];
      *(float4*)&wsh[row * HID_C + c4 * 4] = wf4[(size_t)(kc * 64 + row) * 16 + c4];
    }
    __syncthreads();
#pragma unroll 2
    for (int c4 = 0; c4 < 64; c4 += 4) {
      float4 xv[4], wv[4];
#pragma unroll
      for (int r = 0; r < 4; ++r)
        xv[r] = *(const float4*)&xs[(i0 + r) * XS_LD + c4];
#pragma unroll
      for (int cc = 0; cc < 4; ++cc)
        wv[cc] = *(const float4*)&wsh[(c4 + cc) * HID_C + j0];
#pragma unroll
      for (int r = 0; r < 4; ++r) {
#pragma unroll
        for (int cc = 0; cc < 4; ++cc) {
          float xr = (&xv[r].x)[cc];
          acc[r][0] = fmaf(xr, wv[cc].x, acc[r][0]);
          acc[r][1] = fmaf(xr, wv[cc].y, acc[r][1]);
          acc[r][2] = fmaf(xr, wv[cc].z, acc[r][2]);
          acc[r][3] = fmaf(xr, wv[cc].w, acc[r][3]);
        }
      }
    }
    __syncthreads();
  }
#pragma unroll
  for (int r = 0; r < 4; ++r) {
    int i = rowBase + i0 + r;
    if (i < n) {
      float4 v = make_float4(acc[r][0], acc[r][1], acc[r][2], acc[r][3]);
      *(float4*)&y[(size_t)i * HID_C + j0] = v;
    }
  }
}

// ---- fused: blocks [0,FB): atomic-free CSR fill;
//      blocks [FB,...): y' = dinv * y in place (elementwise) ----
#define FB_BLOCKS 1024
#define SC_BLOCKS 1024
__global__ __launch_bounds__(256) void fused_fill_scale_kernel(
    const int* __restrict__ eidx, int E, const int* __restrict__ rowptr,
    const int* __restrict__ pos, int* __restrict__ csr,
    const float* __restrict__ dinv, float4* __restrict__ y4, int n) {
  int t = threadIdx.x;
  if ((int)blockIdx.x < FB_BLOCKS) {
    // ---- CSR fill, no atomics: csr[rowptr[d] + pos[e]] = s ----
    int base = blockIdx.x * 256 + t;
    int stride = FB_BLOCKS * 256;
    for (int e = base; e < E; e += 4 * stride) {
      int e1 = e + stride, e2 = e + 2 * stride, e3 = e + 3 * stride;
      bool g1 = e1 < E, g2 = e2 < E, g3 = e3 < E;
      int s0 = eidx[e], d0 = eidx[E + e], p0 = pos[e];
      int s1 = 0, d1 = 0, p1 = 0, s2 = 0, d2 = 0, p2 = 0, s3 = 0, d3 = 0, p3 = 0;
      if (g1) { s1 = eidx[e1]; d1 = eidx[E + e1]; p1 = pos[e1]; }
      if (g2) { s2 = eidx[e2]; d2 = eidx[E + e2]; p2 = pos[e2]; }
      if (g3) { s3 = eidx[e3]; d3 = eidx[E + e3]; p3 = pos[e3]; }
      int r0 = rowptr[d0];
      int r1 = g1 ? rowptr[d1] : 0;
      int r2 = g2 ? rowptr[d2] : 0;
      int r3 = g3 ? rowptr[d3] : 0;
      csr[r0 + p0] = s0;
      if (g1) csr[r1 + p1] = s1;
      if (g2) csr[r2 + p2] = s2;
      if (g3) csr[r3 + p3] = s3;
    }
    return;
  }
  // ---- scale: y'[i][*] = dinv[i] * y[i][*]; 16 float4 per row ----
  long long total = (long long)n * 16;
  long long base = (long long)((int)blockIdx.x - FB_BLOCKS) * 256 + t;
  long long stride = (long long)SC_BLOCKS * 256;
  for (long long idx = base; idx < total; idx += stride) {
    int i = (int)(idx >> 4);
    float di = dinv[i];
    float4 v = y4[idx];
    y4[idx] = make_float4(di * v.x, di * v.y, di * v.z, di * v.w);
  }
}

// ---- gather1: h = relu(dinv[i] * Σ y'[s] + b1)  (y' = dinv*y, f32) ----
// wave = node; 4 groups of 16 lanes, each takes every 4th edge, float4 ch;
// next-node rowptr/dinv prefetched (software pipeline)
__global__ __launch_bounds__(256) void gather1_kernel(
    const float4* __restrict__ y4, const int* __restrict__ rowptr,
    const int* __restrict__ csr, const float* __restrict__ dinv,
    const float* __restrict__ b1, float* __restrict__ h, int n) {
  int lane = threadIdx.x & 63;
  int grp = lane >> 4;             // 0..3: edge sub-group
  int q = lane & 15;               // channel quad (4q..4q+3)
  float4 b1v = ((const float4*)b1)[q];
  int wid = (int)((blockIdx.x * blockDim.x + threadIdx.x) >> 6);
  int nw = (int)((gridDim.x * blockDim.x) >> 6);
  int ii = wid;
  int e0 = 0, e1 = 0; float di = 0.f;
  if (ii < n) { e0 = rowptr[ii]; e1 = rowptr[ii + 1]; di = dinv[ii]; }
  while (ii < n) {
    int nxt = ii + nw;
    int ne0 = 0, ne1 = 0; float ndi = 0.f;
    if (nxt < n) { ne0 = rowptr[nxt]; ne1 = rowptr[nxt + 1]; ndi = dinv[nxt]; }
    int i = __builtin_amdgcn_readfirstlane(ii);
    float4 acc = make_float4(0.f, 0.f, 0.f, 0.f);
    if (grp == 0) acc = y4[(size_t)i * 16 + q];       // self term y'[i]
    int e = e0 + grp, end = e1;
    for (; e + 4 < end; e += 8) {
      int s0 = csr[e], s1 = csr[e + 4];
      float4 v0 = y4[(size_t)s0 * 16 + q];
      float4 v1 = y4[(size_t)s1 * 16 + q];
      acc.x += v0.x + v1.x;
      acc.y += v0.y + v1.y;
      acc.z += v0.z + v1.z;
      acc.w += v0.w + v1.w;
    }
    for (; e < end; e += 4) {
      int s = csr[e];
      float4 v = y4[(size_t)s * 16 + q];
      acc.x += v.x; acc.y += v.y; acc.z += v.z; acc.w += v.w;
    }
    // combine groups (xor 16, xor 32)
    acc.x += __shfl_xor(acc.x, 16); acc.y += __shfl_xor(acc.y, 16);
    acc.z += __shfl_xor(acc.z, 16); acc.w += __shfl_xor(acc.w, 16);
    acc.x += __shfl_xor(acc.x, 32); acc.y += __shfl_xor(acc.y, 32);
    acc.z += __shfl_xor(acc.z, 32); acc.w += __shfl_xor(acc.w, 32);
    if (grp == 0) {
      float4 hv;
      hv.x = fmaf(di, acc.x, b1v.x); hv.x = hv.x > 0.f ? hv.x : 0.f;
      hv.y = fmaf(di, acc.y, b1v.y); hv.y = hv.y > 0.f ? hv.y : 0.f;
      hv.z = fmaf(di, acc.z, b1v.z); hv.z = hv.z > 0.f ? hv.z : 0.f;
      hv.w = fmaf(di, acc.w, b1v.w); hv.w = hv.w > 0.f ? hv.w : 0.f;
      *(float4*)&h[(size_t)i * HID_C + 4 * q] = hv;
    }
    ii = nxt; e0 = ne0; e1 = ne1; di = ndi;
  }
}

// ---- z' = dinv * (h @ W2): 64-node x 40-col tile, 4x4 reg tile ----
__global__ __launch_bounds__(256) void gemm2_kernel(
    const float* __restrict__ h, const float* __restrict__ W2,
    const float* __restrict__ dinv, float* __restrict__ z, int n) {
  __shared__ float hs[64 * XS_LD];      // 17.4 KiB
  __shared__ float w2s[64 * OUT_C + 32];  // 10.4 KiB (+pad for idle-lane reads)
  int t = threadIdx.x;
  int rowBase = blockIdx.x * 64;
  const float4* hf4 = (const float4*)h;
  const float4* wf4 = (const float4*)W2;
#pragma unroll
  for (int k = 0; k < 4; ++k) {
    int t4 = t + k * 256;
    int row = t4 >> 4, c4 = t4 & 15;
    int gr = rowBase + row;
    if (gr >= n) gr = n - 1;
    *(float4*)&hs[row * XS_LD + c4 * 4] = hf4[(size_t)gr * 16 + c4];
  }
  for (int t4 = t; t4 < 640; t4 += 256)
    *(float4*)&w2s[t4 * 4] = wf4[t4];
  __syncthreads();
  int tx = t & 15, ty = t >> 4;
  int i0 = ty * 4, j0 = tx * 4;
  bool active = tx < 10;               // 40 cols = 10 quads
  float acc[4][4];
#pragma unroll
  for (int r = 0; r < 4; ++r)
#pragma unroll
    for (int j = 0; j < 4; ++j) acc[r][j] = 0.f;
#pragma unroll 2
  for (int c4 = 0; c4 < 64; c4 += 4) {
    float4 hv[4], wv[4];
#pragma unroll
    for (int r = 0; r < 4; ++r)
      hv[r] = *(const float4*)&hs[(i0 + r) * XS_LD + c4];
#pragma unroll
    for (int cc = 0; cc < 4; ++cc)
      wv[cc] = *(const float4*)&w2s[(c4 + cc) * OUT_C + j0];
#pragma unroll
    for (int r = 0; r < 4; ++r) {
#pragma unroll
      for (int cc = 0; cc < 4; ++cc) {
        float hr = (&hv[r].x)[cc];
        acc[r][0] = fmaf(hr, wv[cc].x, acc[r][0]);
        acc[r][1] = fmaf(hr, wv[cc].y, acc[r][1]);
        acc[r][2] = fmaf(hr, wv[cc].z, acc[r][2]);
        acc[r][3] = fmaf(hr, wv[cc].w, acc[r][3]);
      }
    }
  }
  if (active) {
#pragma unroll
    for (int r = 0; r < 4; ++r) {
      int i = rowBase + i0 + r;
      if (i < n) {
        float di = dinv[i];
        float4 v = make_float4(di * acc[r][0], di * acc[r][1],
                               di * acc[r][2], di * acc[r][3]);
        *(float4*)&z[(size_t)i * OUT_C + j0] = v;
      }
    }
  }
}

// ---- gather(z') + bias + log-softmax: 4 groups, q<10 active, prefetch ----
__global__ __launch_bounds__(256) void gather40_kernel(
    const float4* __restrict__ z4, const int* __restrict__ rowptr,
    const int* __restrict__ csr, const float* __restrict__ dinv,
    const float* __restrict__ b2, float* __restrict__ out, int n) {
  int lane = threadIdx.x & 63;
  int grp = lane >> 4;             // 0..3: edge sub-group
  int q = lane & 15;               // channel quad; active q<10 (40 ch)
  bool act = q < 10;
  float4 b2v = ((const float4*)b2)[act ? q : 0];
  int wid = (int)((blockIdx.x * blockDim.x + threadIdx.x) >> 6);
  int nw = (int)((gridDim.x * blockDim.x) >> 6);
  int ii = wid;
  int e0 = 0, e1 = 0; float di = 0.f;
  if (ii < n) { e0 = rowptr[ii]; e1 = rowptr[ii + 1]; di = dinv[ii]; }
  while (ii < n) {
    int nxt = ii + nw;
    int ne0 = 0, ne1 = 0; float ndi = 0.f;
    if (nxt < n) { ne0 = rowptr[nxt]; ne1 = rowptr[nxt + 1]; ndi = dinv[nxt]; }
    int i = __builtin_amdgcn_readfirstlane(ii);
    float4 acc = make_float4(0.f, 0.f, 0.f, 0.f);
    if (grp == 0 && act) acc = z4[(size_t)i * 10 + q];    // self term z'[i]
    int e = e0 + grp, end = e1;
    if (act) {
      for (; e + 4 < end; e += 8) {
        int s0 = csr[e], s1 = csr[e + 4];
        float4 v0 = z4[(size_t)s0 * 10 + q];
        float4 v1 = z4[(size_t)s1 * 10 + q];
        acc.x += v0.x + v1.x;
        acc.y += v0.y + v1.y;
        acc.z += v0.z + v1.z;
        acc.w += v0.w + v1.w;
      }
      for (; e < end; e += 4) {
        int s = csr[e];
        float4 v = z4[(size_t)s * 10 + q];
        acc.x += v.x; acc.y += v.y; acc.z += v.z; acc.w += v.w;
      }
    }
    // combine groups (inactive lanes hold zeros everywhere)
    acc.x += __shfl_xor(acc.x, 16); acc.y += __shfl_xor(acc.y, 16);
    acc.z += __shfl_xor(acc.z, 16); acc.w += __shfl_xor(acc.w, 16);
    acc.x += __shfl_xor(acc.x, 32); acc.y += __shfl_xor(acc.y, 32);
    acc.z += __shfl_xor(acc.z, 32); acc.w += __shfl_xor(acc.w, 32);
    float4 o;
    o.x = fmaf(di, acc.x, b2v.x);
    o.y = fmaf(di, acc.y, b2v.y);
    o.z = fmaf(di, acc.z, b2v.z);
    o.w = fmaf(di, acc.w, b2v.w);
    // max over 40 ch: per-lane max4, butterfly within 16-lane group
    float m = act ? fmaxf(fmaxf(o.x, o.y), fmaxf(o.z, o.w)) : -INFINITY;
    for (int off = 8; off; off >>= 1) m = fmaxf(m, __shfl_xor(m, off));
    float ex = act ? (expf(o.x - m) + expf(o.y - m) +
                      expf(o.z - m) + expf(o.w - m)) : 0.f;
    float s = ex;
    for (int off = 8; off; off >>= 1) s += __shfl_xor(s, off);
    if (lane < 16 && act) {       // group 0 stores, float4 per lane
      float l = m + logf(s);
      float4 o2 = make_float4(o.x - l, o.y - l, o.z - l, o.w - l);
      *(float4*)&out[(size_t)i * OUT_C + 4 * q] = o2;
    }
    ii = nxt; e0 = ne0; e1 = ne1; di = ndi;
  }
}

extern "C" void kernel_launch(void* const* d_in, const int* in_sizes, int n_in,
                              void* d_out, int out_size, void* d_ws, size_t ws_size,
                              hipStream_t stream) {
  const float* x  = (const float*)d_in[0];
  const int* eidx = (const int*)d_in[1];   // harness delivers integers as int32
  const float* W1 = (const float*)d_in[2];
  const float* b1 = (const float*)d_in[3];
  const float* W2 = (const float*)d_in[4];
  const float* b2 = (const float*)d_in[5];
  float* out = (float*)d_out;

  int n = in_sizes[0] / IN_C;
  int E = in_sizes[1] / 2;

  size_t npad = ((size_t)n + 255) & ~(size_t)255;
  size_t Epad = ((size_t)E + 255) & ~(size_t)255;
  // layout (4-byte units)
  size_t o_dinv   = 0;
  size_t o_deg    = o_dinv + npad;
  size_t o_S      = o_deg + npad;
  size_t o_BS     = o_S + npad;
  size_t o_rowptr = o_BS + 256;
  size_t o_pos    = o_rowptr + npad + 256;
  size_t o_csr    = o_pos + Epad;
  size_t o_bufA   = o_csr + Epad;                 // y/y' then z' (n x 64 f32)
  size_t o_bufC   = o_bufA + (size_t)n * HID_C;   // h (n x 64 f32)
  size_t needed   = (o_bufC + (size_t)n * HID_C) * 4;
  if (ws_size < needed) return;  // fail via absmax, not GPU fault

  float* ws  = (float*)d_ws;
  float* dinv = ws + o_dinv;
  int* deg    = (int*)(ws + o_deg);
  int* S      = (int*)(ws + o_S);
  int* BS     = (int*)(ws + o_BS);
  int* rowptr = (int*)(ws + o_rowptr);
  int* pos    = (int*)(ws + o_pos);
  int* csr    = (int*)(ws + o_csr);
  float* bufA = ws + o_bufA;   // y -> y' (n x 64) -> z' (n x 40)
  float* bufC = ws + o_bufC;   // h (n x 64)

  int nb = (int)((n + 1023) / 1024);   // 98 for n=100k; scan2 supports <=128
  int gemmBlocks = (n + 63) / 64;

  // ---- zero deg; then degpos || gemm1(raw) in one dispatch ----
  zero4_kernel<<<128, 256, 0, stream>>>((int4*)deg, (long long)(npad / 4));
  fused_degpos_gemm1_kernel<<<DP_BLOCKS + gemmBlocks, 256, 0, stream>>>(
      eidx + E, E, deg, pos, x, W1, bufA, n);

  // ---- scans: rowptr + dinv ----
  scan1_kernel<<<nb, 256, 0, stream>>>(deg, S, BS, n);
  scan2_kernel<<<1, 128, 0, stream>>>(BS, nb);
  scan3_kernel<<<(n + 255) / 256, 256, 0, stream>>>(S, BS, deg, rowptr, dinv, n);

  // ---- fill (atomic-free) || y' = dinv * y ----
  fused_fill_scale_kernel<<<FB_BLOCKS + SC_BLOCKS, 256, 0, stream>>>(
      eidx, E, rowptr, pos, csr, dinv, (float4*)bufA, n);

  // ---- layer 1 gather: h = relu(dinv_i * sum(y'_s) + b1) ----
  gather1_kernel<<<2048, 256, 0, stream>>>((const float4*)bufA, rowptr, csr,
                                           dinv, b1, bufC, n);
  // ---- layer 2: z' = dinv*(h@W2) ; out = logsoftmax(dinv*gather(z')+b2) ----
  gemm2_kernel<<<gemmBlocks, 256, 0, stream>>>(bufC, W2, dinv, bufA, n);
  gather40_kernel<<<2048, 256, 0, stream>>>((const float4*)bufA, rowptr, csr,
                                            dinv, b2, out, n);
}

// Round 14
// 184.905 us; speedup vs baseline: 1.0267x; 1.0267x over previous
//
#include <hip/hip_runtime.h>
#include <math.h>

#define IN_C 128
#define HID_C 64
#define OUT_C 40

// ---- grid-stride int4 zero ----
__global__ void zero4_kernel(int4* __restrict__ p, long long n4) {
  long long i = (long long)blockIdx.x * blockDim.x + threadIdx.x;
  long long stride = (long long)gridDim.x * blockDim.x;
  for (; i < n4; i += stride) p[i] = make_int4(0, 0, 0, 0);
}

// ---- scan stage 1: per-1024-chunk inclusive scan + chunk totals ----
__global__ __launch_bounds__(256) void scan1_kernel(
    const int* __restrict__ deg, int* __restrict__ S, int* __restrict__ BS,
    int n) {
  __shared__ int sums[256];
  int t = threadIdx.x;
  int i0 = blockIdx.x * 1024 + t * 4;
  int v0 = (i0 + 0 < n) ? deg[i0 + 0] : 0;
  int v1 = (i0 + 1 < n) ? deg[i0 + 1] : 0;
  int v2 = (i0 + 2 < n) ? deg[i0 + 2] : 0;
  int v3 = (i0 + 3 < n) ? deg[i0 + 3] : 0;
  v1 += v0; v2 += v1; v3 += v2;
  sums[t] = v3;
  __syncthreads();
  for (int off = 1; off < 256; off <<= 1) {
    int x = (t >= off) ? sums[t - off] : 0;
    __syncthreads();
    sums[t] += x;
    __syncthreads();
  }
  int excl = t ? sums[t - 1] : 0;
  if (i0 + 0 < n) S[i0 + 0] = v0 + excl;
  if (i0 + 1 < n) S[i0 + 1] = v1 + excl;
  if (i0 + 2 < n) S[i0 + 2] = v2 + excl;
  if (i0 + 3 < n) S[i0 + 3] = v3 + excl;
  if (t == 255) BS[blockIdx.x] = sums[255];
}

// ---- scan stage 2: exclusive scan of chunk totals (nb <= 128) ----
__global__ __launch_bounds__(128) void scan2_kernel(int* __restrict__ BS,
                                                    int nb) {
  __shared__ int s[128];
  int t = threadIdx.x;
  s[t] = (t < nb) ? BS[t] : 0;
  __syncthreads();
  for (int off = 1; off < 128; off <<= 1) {
    int x = (t >= off) ? s[t - off] : 0;
    __syncthreads();
    s[t] += x;
    __syncthreads();
  }
  if (t < nb) BS[t] = t ? s[t - 1] : 0;
}

// ---- scan stage 3: rowptr + dinv ----
__global__ void scan3_kernel(const int* __restrict__ S,
                             const int* __restrict__ BS,
                             const int* __restrict__ deg,
                             int* __restrict__ rowptr,
                             float* __restrict__ dinv, int n) {
  int i = blockIdx.x * blockDim.x + threadIdx.x;
  if (i < n) {
    int d = deg[i];
    int r = S[i] + BS[i >> 10];      // inclusive prefix = rowptr[i+1]
    rowptr[i + 1] = r;
    dinv[i] = rsqrtf((float)d + 1.0f);
    if (i == 0) rowptr[0] = 0;
  }
}

// ---- fused, INTERLEAVED roles: even blocks (of first 2*DP) = degpos,
//      odd = gemm1; so both are co-resident per CU and truly overlap ----
#define XS_LD 68   // 64 + 4: float4-aligned, banks spread
#define DP_BLOCKS 1024
__global__ __launch_bounds__(256) void fused_degpos_gemm1_kernel(
    const int* __restrict__ dst, int E, int* __restrict__ deg,
    int* __restrict__ pos, const float* __restrict__ x,
    const float* __restrict__ W1, float* __restrict__ y, int n) {
  __shared__ float xs[64 * XS_LD];    // 17.4 KiB
  __shared__ float wsh[64 * HID_C];   // 16 KiB, [k][j]
  int t = threadIdx.x;
  int b = (int)blockIdx.x;
  bool isDP;
  int bi;
  if (b < 2 * DP_BLOCKS) { isDP = (b & 1) == 0; bi = b >> 1; }
  else                   { isDP = false;        bi = b - DP_BLOCKS; }
  if (isDP) {
    // ---- degpos: pos[e] = atomicAdd(deg[dst[e]],1); 4-deep MLP ----
    int base = bi * 256 + t;
    int stride = DP_BLOCKS * 256;
    for (int e = base; e < E; e += 4 * stride) {
      int e1 = e + stride, e2 = e + 2 * stride, e3 = e + 3 * stride;
      bool g1 = e1 < E, g2 = e2 < E, g3 = e3 < E;
      int d0 = dst[e];
      int d1 = g1 ? dst[e1] : 0;
      int d2 = g2 ? dst[e2] : 0;
      int d3 = g3 ? dst[e3] : 0;
      int p0 = atomicAdd(&deg[d0], 1);
      int p1 = g1 ? atomicAdd(&deg[d1], 1) : 0;
      int p2 = g2 ? atomicAdd(&deg[d2], 1) : 0;
      int p3 = g3 ? atomicAdd(&deg[d3], 1) : 0;
      pos[e] = p0;                    // coalesced stores
      if (g1) pos[e1] = p1;
      if (g2) pos[e2] = p2;
      if (g3) pos[e3] = p3;
    }
    return;
  }
  // ---- GEMM1 raw: 64x64 tile, K chunked by 64, 4x4 reg tile ----
  int rowBase = bi * 64;
  if (rowBase >= n) return;
  const float4* xf4 = (const float4*)x;
  const float4* wf4 = (const float4*)W1;
  int tx = t & 15, ty = t >> 4;
  int i0 = ty * 4, j0 = tx * 4;
  float acc[4][4];
#pragma unroll
  for (int r = 0; r < 4; ++r)
#pragma unroll
    for (int j = 0; j < 4; ++j) acc[r][j] = 0.f;

  for (int kc = 0; kc < 2; ++kc) {           // K chunks of 64
#pragma unroll
    for (int k = 0; k < 4; ++k) {
      int t4 = t + k * 256;                  // 0..1023
      int row = t4 >> 4, c4 = t4 & 15;
      int gr = rowBase + row;
      if (gr >= n) gr = n - 1;
      *(float4*)&xs[row * XS_LD + c4 * 4] = xf4[(size_t)gr * 32 + kc * 16 + c4];
      *(float4*)&wsh[row * HID_C + c4 * 4] = wf4[(size_t)(kc * 64 + row) * 16 + c4];
    }
    __syncthreads();
#pragma unroll 2
    for (int c4 = 0; c4 < 64; c4 += 4) {
      float4 xv[4], wv[4];
#pragma unroll
      for (int r = 0; r < 4; ++r)
        xv[r] = *(const float4*)&xs[(i0 + r) * XS_LD + c4];
#pragma unroll
      for (int cc = 0; cc < 4; ++cc)
        wv[cc] = *(const float4*)&wsh[(c4 + cc) * HID_C + j0];
#pragma unroll
      for (int r = 0; r < 4; ++r) {
#pragma unroll
        for (int cc = 0; cc < 4; ++cc) {
          float xr = (&xv[r].x)[cc];
          acc[r][0] = fmaf(xr, wv[cc].x, acc[r][0]);
          acc[r][1] = fmaf(xr, wv[cc].y, acc[r][1]);
          acc[r][2] = fmaf(xr, wv[cc].z, acc[r][2]);
          acc[r][3] = fmaf(xr, wv[cc].w, acc[r][3]);
        }
      }
    }
    __syncthreads();
  }
#pragma unroll
  for (int r = 0; r < 4; ++r) {
    int i = rowBase + i0 + r;
    if (i < n) {
      float4 v = make_float4(acc[r][0], acc[r][1], acc[r][2], acc[r][3]);
      *(float4*)&y[(size_t)i * HID_C + j0] = v;
    }
  }
}

// ---- fused: blocks [0,FB): atomic-free CSR fill;
//      blocks [FB,...): y' = dinv * y in place (elementwise); no LDS ----
#define FB_BLOCKS 1024
#define SC_BLOCKS 1024
__global__ __launch_bounds__(256) void fused_fill_scale_kernel(
    const int* __restrict__ eidx, int E, const int* __restrict__ rowptr,
    const int* __restrict__ pos, int* __restrict__ csr,
    const float* __restrict__ dinv, float4* __restrict__ y4, int n) {
  int t = threadIdx.x;
  if ((int)blockIdx.x < FB_BLOCKS) {
    int base = blockIdx.x * 256 + t;
    int stride = FB_BLOCKS * 256;
    for (int e = base; e < E; e += 4 * stride) {
      int e1 = e + stride, e2 = e + 2 * stride, e3 = e + 3 * stride;
      bool g1 = e1 < E, g2 = e2 < E, g3 = e3 < E;
      int s0 = eidx[e], d0 = eidx[E + e], p0 = pos[e];
      int s1 = 0, d1 = 0, p1 = 0, s2 = 0, d2 = 0, p2 = 0, s3 = 0, d3 = 0, p3 = 0;
      if (g1) { s1 = eidx[e1]; d1 = eidx[E + e1]; p1 = pos[e1]; }
      if (g2) { s2 = eidx[e2]; d2 = eidx[E + e2]; p2 = pos[e2]; }
      if (g3) { s3 = eidx[e3]; d3 = eidx[E + e3]; p3 = pos[e3]; }
      int r0 = rowptr[d0];
      int r1 = g1 ? rowptr[d1] : 0;
      int r2 = g2 ? rowptr[d2] : 0;
      int r3 = g3 ? rowptr[d3] : 0;
      csr[r0 + p0] = s0;
      if (g1) csr[r1 + p1] = s1;
      if (g2) csr[r2 + p2] = s2;
      if (g3) csr[r3 + p3] = s3;
    }
    return;
  }
  // ---- scale: y'[i][*] = dinv[i] * y[i][*]; 16 float4 per row ----
  long long total = (long long)n * 16;
  long long base = (long long)((int)blockIdx.x - FB_BLOCKS) * 256 + t;
  long long stride = (long long)SC_BLOCKS * 256;
  for (long long idx = base; idx < total; idx += stride) {
    int i = (int)(idx >> 4);
    float di = dinv[i];
    float4 v = y4[idx];
    y4[idx] = make_float4(di * v.x, di * v.y, di * v.z, di * v.w);
  }
}

// ---- fused layer-1 gather + gemm2: block owns 64 nodes.
// Phase 1: 4 waves x 16 nodes, gather h rows into LDS (no global h).
// Phase 2: tiled z' = dinv * (h @ W2) from LDS ----
__global__ __launch_bounds__(256) void gather1_gemm2_kernel(
    const float4* __restrict__ y4, const int* __restrict__ rowptr,
    const int* __restrict__ csr, const float* __restrict__ dinv,
    const float* __restrict__ b1, const float* __restrict__ W2,
    float* __restrict__ z, int n) {
  __shared__ float hs[64 * XS_LD];        // 17.4 KiB: h tile
  __shared__ float w2s[64 * OUT_C + 32];  // 10.4 KiB
  int t = threadIdx.x;
  const float4* wf4 = (const float4*)W2;
  for (int t4 = t; t4 < 640; t4 += 256)
    *(float4*)&w2s[t4 * 4] = wf4[t4];
  int lane = t & 63;
  int w = t >> 6;                  // wave 0..3
  int grp = lane >> 4;             // 0..3: edge sub-group
  int q = lane & 15;               // channel quad
  float4 b1v = ((const float4*)b1)[q];
  int rowBase = blockIdx.x * 64;
  // phase 1: gather 16 nodes per wave, software-pipelined metadata
  int idx = rowBase + w * 16;
  int cl = idx < n ? idx : n - 1;
  int e0 = rowptr[cl], e1 = rowptr[cl + 1];
  float di = dinv[cl];
  for (int it = 0; it < 16; ++it) {
    int nidx = idx + 1;
    int ncl = nidx < n ? nidx : n - 1;
    int ne0 = 0, ne1 = 0; float ndi = 0.f;
    if (it < 15) { ne0 = rowptr[ncl]; ne1 = rowptr[ncl + 1]; ndi = dinv[ncl]; }
    int i = __builtin_amdgcn_readfirstlane(cl);
    float4 acc = make_float4(0.f, 0.f, 0.f, 0.f);
    if (grp == 0) acc = y4[(size_t)i * 16 + q];       // self term y'[i]
    int e = e0 + grp, end = e1;
    for (; e + 4 < end; e += 8) {
      int s0 = csr[e], s1 = csr[e + 4];
      float4 v0 = y4[(size_t)s0 * 16 + q];
      float4 v1 = y4[(size_t)s1 * 16 + q];
      acc.x += v0.x + v1.x;
      acc.y += v0.y + v1.y;
      acc.z += v0.z + v1.z;
      acc.w += v0.w + v1.w;
    }
    for (; e < end; e += 4) {
      int s = csr[e];
      float4 v = y4[(size_t)s * 16 + q];
      acc.x += v.x; acc.y += v.y; acc.z += v.z; acc.w += v.w;
    }
    acc.x += __shfl_xor(acc.x, 16); acc.y += __shfl_xor(acc.y, 16);
    acc.z += __shfl_xor(acc.z, 16); acc.w += __shfl_xor(acc.w, 16);
    acc.x += __shfl_xor(acc.x, 32); acc.y += __shfl_xor(acc.y, 32);
    acc.z += __shfl_xor(acc.z, 32); acc.w += __shfl_xor(acc.w, 32);
    if (grp == 0) {
      int r = w * 16 + it;
      float* hr = &hs[r * XS_LD + 4 * q];
      hr[0] = fmaxf(fmaf(di, acc.x, b1v.x), 0.f);
      hr[1] = fmaxf(fmaf(di, acc.y, b1v.y), 0.f);
      hr[2] = fmaxf(fmaf(di, acc.z, b1v.z), 0.f);
      hr[3] = fmaxf(fmaf(di, acc.w, b1v.w), 0.f);
    }
    idx = nidx; cl = ncl; e0 = ne0; e1 = ne1; di = ndi;
  }
  __syncthreads();
  // phase 2: z' = dinv * (h @ W2) from LDS
  int tx = t & 15, ty = t >> 4;
  int i0 = ty * 4, j0 = tx * 4;
  bool active = tx < 10;               // 40 cols = 10 quads
  float acc[4][4];
#pragma unroll
  for (int r = 0; r < 4; ++r)
#pragma unroll
    for (int j = 0; j < 4; ++j) acc[r][j] = 0.f;
#pragma unroll 2
  for (int c4 = 0; c4 < 64; c4 += 4) {
    float4 hv[4], wv[4];
#pragma unroll
    for (int r = 0; r < 4; ++r)
      hv[r] = *(const float4*)&hs[(i0 + r) * XS_LD + c4];
#pragma unroll
    for (int cc = 0; cc < 4; ++cc)
      wv[cc] = *(const float4*)&w2s[(c4 + cc) * OUT_C + j0];
#pragma unroll
    for (int r = 0; r < 4; ++r) {
#pragma unroll
      for (int cc = 0; cc < 4; ++cc) {
        float hr = (&hv[r].x)[cc];
        acc[r][0] = fmaf(hr, wv[cc].x, acc[r][0]);
        acc[r][1] = fmaf(hr, wv[cc].y, acc[r][1]);
        acc[r][2] = fmaf(hr, wv[cc].z, acc[r][2]);
        acc[r][3] = fmaf(hr, wv[cc].w, acc[r][3]);
      }
    }
  }
  if (active) {
#pragma unroll
    for (int r = 0; r < 4; ++r) {
      int i = rowBase + i0 + r;
      if (i < n) {
        float d2 = dinv[i];
        float4 v = make_float4(d2 * acc[r][0], d2 * acc[r][1],
                               d2 * acc[r][2], d2 * acc[r][3]);
        *(float4*)&z[(size_t)i * OUT_C + j0] = v;
      }
    }
  }
}

// ---- gather(z') + bias + log-softmax: 4 groups, q<10 active, prefetch ----
__global__ __launch_bounds__(256) void gather40_kernel(
    const float4* __restrict__ z4, const int* __restrict__ rowptr,
    const int* __restrict__ csr, const float* __restrict__ dinv,
    const float* __restrict__ b2, float* __restrict__ out, int n) {
  int lane = threadIdx.x & 63;
  int grp = lane >> 4;             // 0..3: edge sub-group
  int q = lane & 15;               // channel quad; active q<10 (40 ch)
  bool act = q < 10;
  float4 b2v = ((const float4*)b2)[act ? q : 0];
  int wid = (int)((blockIdx.x * blockDim.x + threadIdx.x) >> 6);
  int nw = (int)((gridDim.x * blockDim.x) >> 6);
  int ii = wid;
  int e0 = 0, e1 = 0; float di = 0.f;
  if (ii < n) { e0 = rowptr[ii]; e1 = rowptr[ii + 1]; di = dinv[ii]; }
  while (ii < n) {
    int nxt = ii + nw;
    int ne0 = 0, ne1 = 0; float ndi = 0.f;
    if (nxt < n) { ne0 = rowptr[nxt]; ne1 = rowptr[nxt + 1]; ndi = dinv[nxt]; }
    int i = __builtin_amdgcn_readfirstlane(ii);
    float4 acc = make_float4(0.f, 0.f, 0.f, 0.f);
    if (grp == 0 && act) acc = z4[(size_t)i * 10 + q];    // self term z'[i]
    int e = e0 + grp, end = e1;
    if (act) {
      for (; e + 4 < end; e += 8) {
        int s0 = csr[e], s1 = csr[e + 4];
        float4 v0 = z4[(size_t)s0 * 10 + q];
        float4 v1 = z4[(size_t)s1 * 10 + q];
        acc.x += v0.x + v1.x;
        acc.y += v0.y + v1.y;
        acc.z += v0.z + v1.z;
        acc.w += v0.w + v1.w;
      }
      for (; e < end; e += 4) {
        int s = csr[e];
        float4 v = z4[(size_t)s * 10 + q];
        acc.x += v.x; acc.y += v.y; acc.z += v.z; acc.w += v.w;
      }
    }
    acc.x += __shfl_xor(acc.x, 16); acc.y += __shfl_xor(acc.y, 16);
    acc.z += __shfl_xor(acc.z, 16); acc.w += __shfl_xor(acc.w, 16);
    acc.x += __shfl_xor(acc.x, 32); acc.y += __shfl_xor(acc.y, 32);
    acc.z += __shfl_xor(acc.z, 32); acc.w += __shfl_xor(acc.w, 32);
    float4 o;
    o.x = fmaf(di, acc.x, b2v.x);
    o.y = fmaf(di, acc.y, b2v.y);
    o.z = fmaf(di, acc.z, b2v.z);
    o.w = fmaf(di, acc.w, b2v.w);
    float m = act ? fmaxf(fmaxf(o.x, o.y), fmaxf(o.z, o.w)) : -INFINITY;
    for (int off = 8; off; off >>= 1) m = fmaxf(m, __shfl_xor(m, off));
    float ex = act ? (expf(o.x - m) + expf(o.y - m) +
                      expf(o.z - m) + expf(o.w - m)) : 0.f;
    float s = ex;
    for (int off = 8; off; off >>= 1) s += __shfl_xor(s, off);
    if (lane < 16 && act) {
      float l = m + logf(s);
      float4 o2 = make_float4(o.x - l, o.y - l, o.z - l, o.w - l);
      *(float4*)&out[(size_t)i * OUT_C + 4 * q] = o2;
    }
    ii = nxt; e0 = ne0; e1 = ne1; di = ndi;
  }
}

extern "C" void kernel_launch(void* const* d_in, const int* in_sizes, int n_in,
                              void* d_out, int out_size, void* d_ws, size_t ws_size,
                              hipStream_t stream) {
  const float* x  = (const float*)d_in[0];
  const int* eidx = (const int*)d_in[1];   // harness delivers integers as int32
  const float* W1 = (const float*)d_in[2];
  const float* b1 = (const float*)d_in[3];
  const float* W2 = (const float*)d_in[4];
  const float* b2 = (const float*)d_in[5];
  float* out = (float*)d_out;

  int n = in_sizes[0] / IN_C;
  int E = in_sizes[1] / 2;

  size_t npad = ((size_t)n + 255) & ~(size_t)255;
  size_t Epad = ((size_t)E + 255) & ~(size_t)255;
  // layout (4-byte units)
  size_t o_dinv   = 0;
  size_t o_deg    = o_dinv + npad;
  size_t o_S      = o_deg + npad;
  size_t o_BS     = o_S + npad;
  size_t o_rowptr = o_BS + 256;
  size_t o_pos    = o_rowptr + npad + 256;
  size_t o_csr    = o_pos + Epad;
  size_t o_bufA   = o_csr + Epad;                 // y -> y' (n x 64 f32)
  size_t o_bufC   = o_bufA + (size_t)n * HID_C;   // z' (n x 40 f32)
  size_t needed   = (o_bufC + (size_t)n * HID_C) * 4;
  if (ws_size < needed) return;  // fail via absmax, not GPU fault

  float* ws  = (float*)d_ws;
  float* dinv = ws + o_dinv;
  int* deg    = (int*)(ws + o_deg);
  int* S      = (int*)(ws + o_S);
  int* BS     = (int*)(ws + o_BS);
  int* rowptr = (int*)(ws + o_rowptr);
  int* pos    = (int*)(ws + o_pos);
  int* csr    = (int*)(ws + o_csr);
  float* bufA = ws + o_bufA;   // y -> y' (n x 64)
  float* bufC = ws + o_bufC;   // z' (n x 40)

  int nb = (int)((n + 1023) / 1024);   // 98 for n=100k; scan2 supports <=128
  int gemmBlocks = (n + 63) / 64;

  // ---- zero deg; then degpos || gemm1(raw), INTERLEAVED ----
  zero4_kernel<<<128, 256, 0, stream>>>((int4*)deg, (long long)(npad / 4));
  fused_degpos_gemm1_kernel<<<DP_BLOCKS + gemmBlocks, 256, 0, stream>>>(
      eidx + E, E, deg, pos, x, W1, bufA, n);

  // ---- scans: rowptr + dinv ----
  scan1_kernel<<<nb, 256, 0, stream>>>(deg, S, BS, n);
  scan2_kernel<<<1, 128, 0, stream>>>(BS, nb);
  scan3_kernel<<<(n + 255) / 256, 256, 0, stream>>>(S, BS, deg, rowptr, dinv, n);

  // ---- fill (atomic-free) || y' = dinv * y ----
  fused_fill_scale_kernel<<<FB_BLOCKS + SC_BLOCKS, 256, 0, stream>>>(
      eidx, E, rowptr, pos, csr, dinv, (float4*)bufA, n);

  // ---- layer 1 gather + gemm2 fused (h stays in LDS); z' -> bufC ----
  gather1_gemm2_kernel<<<gemmBlocks, 256, 0, stream>>>(
      (const float4*)bufA, rowptr, csr, dinv, b1, W2, bufC, n);

  // ---- gather(z') + bias + log-softmax ----
  gather40_kernel<<<2048, 256, 0, stream>>>((const float4*)bufC, rowptr, csr,
                                            dinv, b2, out, n);
}

// Round 15
// 165.966 us; speedup vs baseline: 1.1439x; 1.1141x over previous
//
#include <hip/hip_runtime.h>
#include <math.h>

#define IN_C 128
#define HID_C 64
#define OUT_C 40

typedef unsigned short u16;
__device__ __forceinline__ float bf2f(u16 u) {
  return __uint_as_float(((unsigned int)u) << 16);
}
__device__ __forceinline__ u16 f2bf(float f) {
  unsigned int u = __float_as_uint(f);
  u += 0x7fffu + ((u >> 16) & 1u);   // round to nearest even
  return (u16)(u >> 16);
}

// ---- grid-stride int4 zero ----
__global__ void zero4_kernel(int4* __restrict__ p, long long n4) {
  long long i = (long long)blockIdx.x * blockDim.x + threadIdx.x;
  long long stride = (long long)gridDim.x * blockDim.x;
  for (; i < n4; i += stride) p[i] = make_int4(0, 0, 0, 0);
}

// ---- scan stage 1: per-1024-chunk inclusive scan + chunk totals ----
__global__ __launch_bounds__(256) void scan1_kernel(
    const int* __restrict__ deg, int* __restrict__ S, int* __restrict__ BS,
    int n) {
  __shared__ int sums[256];
  int t = threadIdx.x;
  int i0 = blockIdx.x * 1024 + t * 4;
  int v0 = (i0 + 0 < n) ? deg[i0 + 0] : 0;
  int v1 = (i0 + 1 < n) ? deg[i0 + 1] : 0;
  int v2 = (i0 + 2 < n) ? deg[i0 + 2] : 0;
  int v3 = (i0 + 3 < n) ? deg[i0 + 3] : 0;
  v1 += v0; v2 += v1; v3 += v2;
  sums[t] = v3;
  __syncthreads();
  for (int off = 1; off < 256; off <<= 1) {
    int x = (t >= off) ? sums[t - off] : 0;
    __syncthreads();
    sums[t] += x;
    __syncthreads();
  }
  int excl = t ? sums[t - 1] : 0;
  if (i0 + 0 < n) S[i0 + 0] = v0 + excl;
  if (i0 + 1 < n) S[i0 + 1] = v1 + excl;
  if (i0 + 2 < n) S[i0 + 2] = v2 + excl;
  if (i0 + 3 < n) S[i0 + 3] = v3 + excl;
  if (t == 255) BS[blockIdx.x] = sums[255];
}

// ---- scan stage 2: exclusive scan of chunk totals (nb <= 128) ----
__global__ __launch_bounds__(128) void scan2_kernel(int* __restrict__ BS,
                                                    int nb) {
  __shared__ int s[128];
  int t = threadIdx.x;
  s[t] = (t < nb) ? BS[t] : 0;
  __syncthreads();
  for (int off = 1; off < 128; off <<= 1) {
    int x = (t >= off) ? s[t - off] : 0;
    __syncthreads();
    s[t] += x;
    __syncthreads();
  }
  if (t < nb) BS[t] = t ? s[t - 1] : 0;
}

// ---- scan stage 3: rowptr + dinv ----
__global__ void scan3_kernel(const int* __restrict__ S,
                             const int* __restrict__ BS,
                             const int* __restrict__ deg,
                             int* __restrict__ rowptr,
                             float* __restrict__ dinv, int n) {
  int i = blockIdx.x * blockDim.x + threadIdx.x;
  if (i < n) {
    int d = deg[i];
    int r = S[i] + BS[i >> 10];      // inclusive prefix = rowptr[i+1]
    rowptr[i + 1] = r;
    dinv[i] = rsqrtf((float)d + 1.0f);
    if (i == 0) rowptr[0] = 0;
  }
}

// ---- fused, INTERLEAVED roles: even blocks (of first 2*DP) = degpos,
//      odd = gemm1; both co-resident per CU and truly overlapping ----
#define XS_LD 68   // 64 + 4: float4-aligned, banks spread
#define DP_BLOCKS 1024
__global__ __launch_bounds__(256) void fused_degpos_gemm1_kernel(
    const int* __restrict__ dst, int E, int* __restrict__ deg,
    int* __restrict__ pos, const float* __restrict__ x,
    const float* __restrict__ W1, float* __restrict__ y, int n) {
  __shared__ float xs[64 * XS_LD];    // 17.4 KiB
  __shared__ float wsh[64 * HID_C];   // 16 KiB, [k][j]
  int t = threadIdx.x;
  int b = (int)blockIdx.x;
  bool isDP;
  int bi;
  if (b < 2 * DP_BLOCKS) { isDP = (b & 1) == 0; bi = b >> 1; }
  else                   { isDP = false;        bi = b - DP_BLOCKS; }
  if (isDP) {
    // ---- degpos: pos[e] = atomicAdd(deg[dst[e]],1); 4-deep MLP ----
    int base = bi * 256 + t;
    int stride = DP_BLOCKS * 256;
    for (int e = base; e < E; e += 4 * stride) {
      int e1 = e + stride, e2 = e + 2 * stride, e3 = e + 3 * stride;
      bool g1 = e1 < E, g2 = e2 < E, g3 = e3 < E;
      int d0 = dst[e];
      int d1 = g1 ? dst[e1] : 0;
      int d2 = g2 ? dst[e2] : 0;
      int d3 = g3 ? dst[e3] : 0;
      int p0 = atomicAdd(&deg[d0], 1);
      int p1 = g1 ? atomicAdd(&deg[d1], 1) : 0;
      int p2 = g2 ? atomicAdd(&deg[d2], 1) : 0;
      int p3 = g3 ? atomicAdd(&deg[d3], 1) : 0;
      pos[e] = p0;                    // coalesced stores
      if (g1) pos[e1] = p1;
      if (g2) pos[e2] = p2;
      if (g3) pos[e3] = p3;
    }
    return;
  }
  // ---- GEMM1 raw: 64x64 tile, K chunked by 64, 4x4 reg tile ----
  int rowBase = bi * 64;
  if (rowBase >= n) return;
  const float4* xf4 = (const float4*)x;
  const float4* wf4 = (const float4*)W1;
  int tx = t & 15, ty = t >> 4;
  int i0 = ty * 4, j0 = tx * 4;
  float acc[4][4];
#pragma unroll
  for (int r = 0; r < 4; ++r)
#pragma unroll
    for (int j = 0; j < 4; ++j) acc[r][j] = 0.f;

  for (int kc = 0; kc < 2; ++kc) {           // K chunks of 64
#pragma unroll
    for (int k = 0; k < 4; ++k) {
      int t4 = t + k * 256;                  // 0..1023
      int row = t4 >> 4, c4 = t4 & 15;
      int gr = rowBase + row;
      if (gr >= n) gr = n - 1;
      *(float4*)&xs[row * XS_LD + c4 * 4] = xf4[(size_t)gr * 32 + kc * 16 + c4];
      *(float4*)&wsh[row * HID_C + c4 * 4] = wf4[(size_t)(kc * 64 + row) * 16 + c4];
    }
    __syncthreads();
#pragma unroll 2
    for (int c4 = 0; c4 < 64; c4 += 4) {
      float4 xv[4], wv[4];
#pragma unroll
      for (int r = 0; r < 4; ++r)
        xv[r] = *(const float4*)&xs[(i0 + r) * XS_LD + c4];
#pragma unroll
      for (int cc = 0; cc < 4; ++cc)
        wv[cc] = *(const float4*)&wsh[(c4 + cc) * HID_C + j0];
#pragma unroll
      for (int r = 0; r < 4; ++r) {
#pragma unroll
        for (int cc = 0; cc < 4; ++cc) {
          float xr = (&xv[r].x)[cc];
          acc[r][0] = fmaf(xr, wv[cc].x, acc[r][0]);
          acc[r][1] = fmaf(xr, wv[cc].y, acc[r][1]);
          acc[r][2] = fmaf(xr, wv[cc].z, acc[r][2]);
          acc[r][3] = fmaf(xr, wv[cc].w, acc[r][3]);
        }
      }
    }
    __syncthreads();
  }
#pragma unroll
  for (int r = 0; r < 4; ++r) {
    int i = rowBase + i0 + r;
    if (i < n) {
      float4 v = make_float4(acc[r][0], acc[r][1], acc[r][2], acc[r][3]);
      *(float4*)&y[(size_t)i * HID_C + j0] = v;
    }
  }
}

// ---- fused: blocks [0,FB): atomic-free CSR fill;
//      blocks [FB,...): y' = bf16(dinv * y) (elementwise); no LDS ----
#define FB_BLOCKS 1024
#define SC_BLOCKS 1024
__global__ __launch_bounds__(256) void fused_fill_scale_kernel(
    const int* __restrict__ eidx, int E, const int* __restrict__ rowptr,
    const int* __restrict__ pos, int* __restrict__ csr,
    const float* __restrict__ dinv, const float4* __restrict__ y4,
    ushort4* __restrict__ ybf, int n) {
  int t = threadIdx.x;
  if ((int)blockIdx.x < FB_BLOCKS) {
    int base = blockIdx.x * 256 + t;
    int stride = FB_BLOCKS * 256;
    for (int e = base; e < E; e += 4 * stride) {
      int e1 = e + stride, e2 = e + 2 * stride, e3 = e + 3 * stride;
      bool g1 = e1 < E, g2 = e2 < E, g3 = e3 < E;
      int s0 = eidx[e], d0 = eidx[E + e], p0 = pos[e];
      int s1 = 0, d1 = 0, p1 = 0, s2 = 0, d2 = 0, p2 = 0, s3 = 0, d3 = 0, p3 = 0;
      if (g1) { s1 = eidx[e1]; d1 = eidx[E + e1]; p1 = pos[e1]; }
      if (g2) { s2 = eidx[e2]; d2 = eidx[E + e2]; p2 = pos[e2]; }
      if (g3) { s3 = eidx[e3]; d3 = eidx[E + e3]; p3 = pos[e3]; }
      int r0 = rowptr[d0];
      int r1 = g1 ? rowptr[d1] : 0;
      int r2 = g2 ? rowptr[d2] : 0;
      int r3 = g3 ? rowptr[d3] : 0;
      csr[r0 + p0] = s0;
      if (g1) csr[r1 + p1] = s1;
      if (g2) csr[r2 + p2] = s2;
      if (g3) csr[r3 + p3] = s3;
    }
    return;
  }
  // ---- scale+cast: ybf[idx] = bf16(dinv[i] * y[idx]); 16 float4 per row ----
  long long total = (long long)n * 16;
  long long base = (long long)((int)blockIdx.x - FB_BLOCKS) * 256 + t;
  long long stride = (long long)SC_BLOCKS * 256;
  for (long long idx = base; idx < total; idx += stride) {
    int i = (int)(idx >> 4);
    float di = dinv[i];
    float4 v = y4[idx];
    ushort4 u;
    u.x = f2bf(di * v.x);
    u.y = f2bf(di * v.y);
    u.z = f2bf(di * v.z);
    u.w = f2bf(di * v.w);
    ybf[idx] = u;
  }
}

// ---- gather1: h = relu(dinv[i] * Σ y'[s] + b1)  (y' bf16, 128B rows) ----
// wave = node; 4 groups of 16 lanes, each takes every 4th edge, ushort4 ch;
// next-node rowptr/dinv prefetched (software pipeline)
__global__ __launch_bounds__(256) void gather1_kernel(
    const ushort4* __restrict__ y4, const int* __restrict__ rowptr,
    const int* __restrict__ csr, const float* __restrict__ dinv,
    const float* __restrict__ b1, float* __restrict__ h, int n) {
  int lane = threadIdx.x & 63;
  int grp = lane >> 4;             // 0..3: edge sub-group
  int q = lane & 15;               // channel quad (4q..4q+3)
  float4 b1v = ((const float4*)b1)[q];
  int wid = (int)((blockIdx.x * blockDim.x + threadIdx.x) >> 6);
  int nw = (int)((gridDim.x * blockDim.x) >> 6);
  int ii = wid;
  int e0 = 0, e1 = 0; float di = 0.f;
  if (ii < n) { e0 = rowptr[ii]; e1 = rowptr[ii + 1]; di = dinv[ii]; }
  while (ii < n) {
    int nxt = ii + nw;
    int ne0 = 0, ne1 = 0; float ndi = 0.f;
    if (nxt < n) { ne0 = rowptr[nxt]; ne1 = rowptr[nxt + 1]; ndi = dinv[nxt]; }
    int i = __builtin_amdgcn_readfirstlane(ii);
    float4 acc = make_float4(0.f, 0.f, 0.f, 0.f);
    if (grp == 0) {                // self term y'[i]
      ushort4 u = y4[(size_t)i * 16 + q];
      acc.x = bf2f(u.x); acc.y = bf2f(u.y); acc.z = bf2f(u.z); acc.w = bf2f(u.w);
    }
    int e = e0 + grp, end = e1;
    for (; e + 4 < end; e += 8) {
      int s0 = csr[e], s1 = csr[e + 4];
      ushort4 u0 = y4[(size_t)s0 * 16 + q];
      ushort4 u1 = y4[(size_t)s1 * 16 + q];
      acc.x += bf2f(u0.x) + bf2f(u1.x);
      acc.y += bf2f(u0.y) + bf2f(u1.y);
      acc.z += bf2f(u0.z) + bf2f(u1.z);
      acc.w += bf2f(u0.w) + bf2f(u1.w);
    }
    for (; e < end; e += 4) {
      int s = csr[e];
      ushort4 u = y4[(size_t)s * 16 + q];
      acc.x += bf2f(u.x); acc.y += bf2f(u.y);
      acc.z += bf2f(u.z); acc.w += bf2f(u.w);
    }
    // combine groups (xor 16, xor 32)
    acc.x += __shfl_xor(acc.x, 16); acc.y += __shfl_xor(acc.y, 16);
    acc.z += __shfl_xor(acc.z, 16); acc.w += __shfl_xor(acc.w, 16);
    acc.x += __shfl_xor(acc.x, 32); acc.y += __shfl_xor(acc.y, 32);
    acc.z += __shfl_xor(acc.z, 32); acc.w += __shfl_xor(acc.w, 32);
    if (grp == 0) {
      float4 hv;
      hv.x = fmaxf(fmaf(di, acc.x, b1v.x), 0.f);
      hv.y = fmaxf(fmaf(di, acc.y, b1v.y), 0.f);
      hv.z = fmaxf(fmaf(di, acc.z, b1v.z), 0.f);
      hv.w = fmaxf(fmaf(di, acc.w, b1v.w), 0.f);
      *(float4*)&h[(size_t)i * HID_C + 4 * q] = hv;
    }
    ii = nxt; e0 = ne0; e1 = ne1; di = ndi;
  }
}

// ---- z' = dinv * (h @ W2): 64-node x 40-col tile, 4x4 reg tile ----
__global__ __launch_bounds__(256) void gemm2_kernel(
    const float* __restrict__ h, const float* __restrict__ W2,
    const float* __restrict__ dinv, float* __restrict__ z, int n) {
  __shared__ float hs[64 * XS_LD];      // 17.4 KiB
  __shared__ float w2s[64 * OUT_C + 32];  // 10.4 KiB
  int t = threadIdx.x;
  int rowBase = blockIdx.x * 64;
  const float4* hf4 = (const float4*)h;
  const float4* wf4 = (const float4*)W2;
#pragma unroll
  for (int k = 0; k < 4; ++k) {
    int t4 = t + k * 256;
    int row = t4 >> 4, c4 = t4 & 15;
    int gr = rowBase + row;
    if (gr >= n) gr = n - 1;
    *(float4*)&hs[row * XS_LD + c4 * 4] = hf4[(size_t)gr * 16 + c4];
  }
  for (int t4 = t; t4 < 640; t4 += 256)
    *(float4*)&w2s[t4 * 4] = wf4[t4];
  __syncthreads();
  int tx = t & 15, ty = t >> 4;
  int i0 = ty * 4, j0 = tx * 4;
  bool active = tx < 10;               // 40 cols = 10 quads
  float acc[4][4];
#pragma unroll
  for (int r = 0; r < 4; ++r)
#pragma unroll
    for (int j = 0; j < 4; ++j) acc[r][j] = 0.f;
#pragma unroll 2
  for (int c4 = 0; c4 < 64; c4 += 4) {
    float4 hv[4], wv[4];
#pragma unroll
    for (int r = 0; r < 4; ++r)
      hv[r] = *(const float4*)&hs[(i0 + r) * XS_LD + c4];
#pragma unroll
    for (int cc = 0; cc < 4; ++cc)
      wv[cc] = *(const float4*)&w2s[(c4 + cc) * OUT_C + j0];
#pragma unroll
    for (int r = 0; r < 4; ++r) {
#pragma unroll
      for (int cc = 0; cc < 4; ++cc) {
        float hr = (&hv[r].x)[cc];
        acc[r][0] = fmaf(hr, wv[cc].x, acc[r][0]);
        acc[r][1] = fmaf(hr, wv[cc].y, acc[r][1]);
        acc[r][2] = fmaf(hr, wv[cc].z, acc[r][2]);
        acc[r][3] = fmaf(hr, wv[cc].w, acc[r][3]);
      }
    }
  }
  if (active) {
#pragma unroll
    for (int r = 0; r < 4; ++r) {
      int i = rowBase + i0 + r;
      if (i < n) {
        float d2 = dinv[i];
        float4 v = make_float4(d2 * acc[r][0], d2 * acc[r][1],
                               d2 * acc[r][2], d2 * acc[r][3]);
        *(float4*)&z[(size_t)i * OUT_C + j0] = v;
      }
    }
  }
}

// ---- gather(z' f32) + bias + log-softmax: 4 groups, q<10 active ----
__global__ __launch_bounds__(256) void gather40_kernel(
    const float4* __restrict__ z4, const int* __restrict__ rowptr,
    const int* __restrict__ csr, const float* __restrict__ dinv,
    const float* __restrict__ b2, float* __restrict__ out, int n) {
  int lane = threadIdx.x & 63;
  int grp = lane >> 4;             // 0..3: edge sub-group
  int q = lane & 15;               // channel quad; active q<10 (40 ch)
  bool act = q < 10;
  float4 b2v = ((const float4*)b2)[act ? q : 0];
  int wid = (int)((blockIdx.x * blockDim.x + threadIdx.x) >> 6);
  int nw = (int)((gridDim.x * blockDim.x) >> 6);
  int ii = wid;
  int e0 = 0, e1 = 0; float di = 0.f;
  if (ii < n) { e0 = rowptr[ii]; e1 = rowptr[ii + 1]; di = dinv[ii]; }
  while (ii < n) {
    int nxt = ii + nw;
    int ne0 = 0, ne1 = 0; float ndi = 0.f;
    if (nxt < n) { ne0 = rowptr[nxt]; ne1 = rowptr[nxt + 1]; ndi = dinv[nxt]; }
    int i = __builtin_amdgcn_readfirstlane(ii);
    float4 acc = make_float4(0.f, 0.f, 0.f, 0.f);
    if (grp == 0 && act) acc = z4[(size_t)i * 10 + q];    // self term z'[i]
    int e = e0 + grp, end = e1;
    if (act) {
      for (; e + 4 < end; e += 8) {
        int s0 = csr[e], s1 = csr[e + 4];
        float4 v0 = z4[(size_t)s0 * 10 + q];
        float4 v1 = z4[(size_t)s1 * 10 + q];
        acc.x += v0.x + v1.x;
        acc.y += v0.y + v1.y;
        acc.z += v0.z + v1.z;
        acc.w += v0.w + v1.w;
      }
      for (; e < end; e += 4) {
        int s = csr[e];
        float4 v = z4[(size_t)s * 10 + q];
        acc.x += v.x; acc.y += v.y; acc.z += v.z; acc.w += v.w;
      }
    }
    acc.x += __shfl_xor(acc.x, 16); acc.y += __shfl_xor(acc.y, 16);
    acc.z += __shfl_xor(acc.z, 16); acc.w += __shfl_xor(acc.w, 16);
    acc.x += __shfl_xor(acc.x, 32); acc.y += __shfl_xor(acc.y, 32);
    acc.z += __shfl_xor(acc.z, 32); acc.w += __shfl_xor(acc.w, 32);
    float4 o;
    o.x = fmaf(di, acc.x, b2v.x);
    o.y = fmaf(di, acc.y, b2v.y);
    o.z = fmaf(di, acc.z, b2v.z);
    o.w = fmaf(di, acc.w, b2v.w);
    float m = act ? fmaxf(fmaxf(o.x, o.y), fmaxf(o.z, o.w)) : -INFINITY;
    for (int off = 8; off; off >>= 1) m = fmaxf(m, __shfl_xor(m, off));
    float ex = act ? (expf(o.x - m) + expf(o.y - m) +
                      expf(o.z - m) + expf(o.w - m)) : 0.f;
    float s = ex;
    for (int off = 8; off; off >>= 1) s += __shfl_xor(s, off);
    if (lane < 16 && act) {
      float l = m + logf(s);
      float4 o2 = make_float4(o.x - l, o.y - l, o.z - l, o.w - l);
      *(float4*)&out[(size_t)i * OUT_C + 4 * q] = o2;
    }
    ii = nxt; e0 = ne0; e1 = ne1; di = ndi;
  }
}

extern "C" void kernel_launch(void* const* d_in, const int* in_sizes, int n_in,
                              void* d_out, int out_size, void* d_ws, size_t ws_size,
                              hipStream_t stream) {
  const float* x  = (const float*)d_in[0];
  const int* eidx = (const int*)d_in[1];   // harness delivers integers as int32
  const float* W1 = (const float*)d_in[2];
  const float* b1 = (const float*)d_in[3];
  const float* W2 = (const float*)d_in[4];
  const float* b2 = (const float*)d_in[5];
  float* out = (float*)d_out;

  int n = in_sizes[0] / IN_C;
  int E = in_sizes[1] / 2;

  size_t npad = ((size_t)n + 255) & ~(size_t)255;
  size_t Epad = ((size_t)E + 255) & ~(size_t)255;
  // layout (4-byte units)
  size_t o_dinv   = 0;
  size_t o_deg    = o_dinv + npad;
  size_t o_S      = o_deg + npad;
  size_t o_BS     = o_S + npad;
  size_t o_rowptr = o_BS + 256;
  size_t o_pos    = o_rowptr + npad + 256;
  size_t o_csr    = o_pos + Epad;
  size_t o_bufA   = o_csr + Epad;                 // y raw f32 -> h f32 (n x 64)
  size_t o_bufC   = o_bufA + (size_t)n * HID_C;   // y' bf16 (n*32 w) -> z' f32 (n*40 w)
  size_t needed   = (o_bufC + (size_t)n * HID_C) * 4;
  if (ws_size < needed) return;  // fail via absmax, not GPU fault

  float* ws  = (float*)d_ws;
  float* dinv = ws + o_dinv;
  int* deg    = (int*)(ws + o_deg);
  int* S      = (int*)(ws + o_S);
  int* BS     = (int*)(ws + o_BS);
  int* rowptr = (int*)(ws + o_rowptr);
  int* pos    = (int*)(ws + o_pos);
  int* csr    = (int*)(ws + o_csr);
  float* bufA = ws + o_bufA;   // y (f32) then h (f32)
  float* bufC = ws + o_bufC;   // y' (bf16) then z' (f32)

  int nb = (int)((n + 1023) / 1024);   // 98 for n=100k; scan2 supports <=128
  int gemmBlocks = (n + 63) / 64;

  // ---- zero deg; then degpos || gemm1(raw), INTERLEAVED ----
  zero4_kernel<<<128, 256, 0, stream>>>((int4*)deg, (long long)(npad / 4));
  fused_degpos_gemm1_kernel<<<DP_BLOCKS + gemmBlocks, 256, 0, stream>>>(
      eidx + E, E, deg, pos, x, W1, bufA, n);

  // ---- scans: rowptr + dinv ----
  scan1_kernel<<<nb, 256, 0, stream>>>(deg, S, BS, n);
  scan2_kernel<<<1, 128, 0, stream>>>(BS, nb);
  scan3_kernel<<<(n + 255) / 256, 256, 0, stream>>>(S, BS, deg, rowptr, dinv, n);

  // ---- fill (atomic-free) || y' = bf16(dinv * y) ----
  fused_fill_scale_kernel<<<FB_BLOCKS + SC_BLOCKS, 256, 0, stream>>>(
      eidx, E, rowptr, pos, csr, dinv, (const float4*)bufA, (ushort4*)bufC, n);

  // ---- layer 1 gather (bf16 rows): h -> bufA (y dead) ----
  gather1_kernel<<<2048, 256, 0, stream>>>((const ushort4*)bufC, rowptr, csr,
                                           dinv, b1, bufA, n);
  // ---- layer 2: z' = dinv*(h@W2) -> bufC ; out = logsoftmax(...) ----
  gemm2_kernel<<<gemmBlocks, 256, 0, stream>>>(bufA, W2, dinv, bufC, n);
  gather40_kernel<<<2048, 256, 0, stream>>>((const float4*)bufC, rowptr, csr,
                                            dinv, b2, out, n);
}